// Round 3
// baseline (320.556 us; speedup 1.0000x reference)
//
#include <hip/hip_runtime.h>
#include <hip/hip_bf16.h>
#include <stdint.h>

#define B_ 32
#define T_ 2048
#define D_ 128
#define BQ 128
#define BK 32
#define NQB (T_ / BQ)            // 16 q-blocks per batch
#define NTASK (B_ * NQB)         // 512 tasks
#define GRIDP 1024               // persistent blocks (4/CU target)

typedef __attribute__((ext_vector_type(8))) __bf16 bf16x8;
typedef __attribute__((ext_vector_type(16))) float f32x16;

// dynamic work queue (self-resetting across graph replays: last finisher resets)
__device__ int g_ctr  = 0;
__device__ int g_done = 0;

__device__ __forceinline__ float fast_exp2(float x) {
#if __has_builtin(__builtin_amdgcn_exp2f)
    return __builtin_amdgcn_exp2f(x);
#else
    return exp2f(x);
#endif
}

__device__ __forceinline__ f32x16 zero16() {
    f32x16 z;
    #pragma unroll
    for (int i = 0; i < 16; ++i) z[i] = 0.f;
    return z;
}

// pack two f32 -> one u32 of 2x bf16 (compiler emits v_cvt_pk_bf16_f32)
__device__ __forceinline__ uint32_t pk2(float a, float b) {
    union { __hip_bfloat16 h; unsigned short u; } ua, ub;
    ua.h = __float2bfloat16(a); ub.h = __float2bfloat16(b);
    return (uint32_t)ua.u | ((uint32_t)ub.u << 16);
}

// swap lane-halves between two regs (gfx950)
__device__ __forceinline__ void plswap(uint32_t& a, uint32_t& b) {
    asm("v_permlane32_swap_b32 %0, %1" : "+v"(a), "+v"(b));
}

// async global->LDS, 16B per lane, LDS dest = wave-uniform base + lane*16 (linear)
__device__ __forceinline__ void gll16(const __hip_bfloat16* g, __hip_bfloat16* lds) {
    __builtin_amdgcn_global_load_lds(
        (const __attribute__((address_space(1))) uint32_t*)g,
        (__attribute__((address_space(3))) uint32_t*)lds,
        16, 0, 0);
}

// ---------------- fused prep: K fp32->bf16 (same layout) + V fp32 -> VT bf16 [b][d][k] ----------------
__global__ __launch_bounds__(256, 2)
void prep(const float* __restrict__ K, const float* __restrict__ V,
          const int* __restrict__ vlens,
          __hip_bfloat16* __restrict__ Kb, __hip_bfloat16* __restrict__ VTb)
{
    __shared__ float tile[64][132];                // 132: float4-aligned rows
    const int b = blockIdx.y, k0 = blockIdx.x * 64;
    const int kmax = (vlens[b] + 63) & ~63;        // attn never reads past ceil64(vlen)
    if (k0 >= kmax) return;

    // --- K: straight convert, coalesced ---
    {
        const float4* src = (const float4*)(K + ((size_t)b * T_ + k0) * D_);
        uint2* dst = (uint2*)(Kb + ((size_t)b * T_ + k0) * D_);
        #pragma unroll
        for (int it = 0; it < 8; ++it) {
            int c = it * 256 + threadIdx.x;        // 2048 float4 chunks
            float4 v = src[c];
            union { __hip_bfloat16 h[4]; uint2 u; } pk;
            pk.h[0] = __float2bfloat16(v.x); pk.h[1] = __float2bfloat16(v.y);
            pk.h[2] = __float2bfloat16(v.z); pk.h[3] = __float2bfloat16(v.w);
            dst[c] = pk.u;
        }
    }

    // --- V: LDS transpose ---
    {
        const float4* src = (const float4*)(V + ((size_t)b * T_ + k0) * D_);
        #pragma unroll
        for (int it = 0; it < 8; ++it) {
            int c = it * 256 + threadIdx.x;
            int row = c >> 5, c4 = c & 31;
            *(float4*)&tile[row][c4 * 4] = src[c];
        }
        __syncthreads();
        #pragma unroll
        for (int it = 0; it < 8; ++it) {
            int c = it * 256 + threadIdx.x;        // 2048 chunks of 4 keys
            int kc = c & 15, d = c >> 4;
            union { __hip_bfloat16 h[4]; uint2 u; } pk;
            #pragma unroll
            for (int j = 0; j < 4; ++j) {
                int jj = (j + kc) & 3;             // rotate reads to spread LDS banks
                pk.h[jj] = __float2bfloat16(tile[kc * 4 + jj][d]);
            }
            *(uint2*)(VTb + ((size_t)b * D_ + d) * T_ + k0 + kc * 4) = pk.u;
        }
    }
}

// ---------------- main: persistent flash attention, 4 waves x 32 q-rows, BK=32, 32x32x16 MFMA ----------------
// SWAPPED QK^T: S = mfma(K, Q) -> C[m=key][n=q], col(lane&31)=q, row=key via
// (r&3)+8*(r>>2)+4*hi [harness-verified rounds 1-2]. Lane owns P[*][q=lane&31] ->
// softmax + P->bf16 A-frags in-register (pk2 + permlane32_swap). Staging via
// global_load_lds (no staging VGPRs); both-sides XOR swizzle on 16B slots
// (K rows 256B: s^(row&7); V rows 64B: s^((row>>1)&3)). Double-buffered, ONE
// barrier per k-iter. BK=32 -> LDS 33 KiB -> 4 blocks/CU (4 independent barrier
// groups). Dynamic task queue balances variable vlen work; batch-major task
// order keeps concurrent tasks on the same ~1 MB K/V working set (L2-resident).
__global__ __launch_bounds__(256, 4)
void attn_main(const float* __restrict__ Q, const int* __restrict__ vlens,
               const __hip_bfloat16* __restrict__ Kb,
               const __hip_bfloat16* __restrict__ VTb,
               float* __restrict__ out)
{
    const int tid  = threadIdx.x;
    const int wave = tid >> 6;          // 0..3, owns q-rows [wave*32, wave*32+32)
    const int lane = tid & 63;
    const int l32  = lane & 31;
    const int hi   = lane >> 5;

    __shared__ __hip_bfloat16 sK [2][BK][128];   // K tile  [key][d]   2x8 KiB
    __shared__ __hip_bfloat16 sVT[2][128][BK];   // V tile  [d][key]   2x8 KiB
    __shared__ int s_task;

    const float C = 1.4426950408889634f / 256.0f;  // log2(e) / (2*d)

    for (;;) {
        if (tid == 0) s_task = atomicAdd(&g_ctr, 1);
        __syncthreads();
        const int task = s_task;
        __syncthreads();                 // s_task consumed before next overwrite
        if (task >= NTASK) break;

        const int b    = task >> 4;      // batch-major: consecutive tasks share batch
        const int q0   = (task & (NQB - 1)) * BQ;
        const int vlen = vlens[b];
        const int nkb  = (vlen + BK - 1) / BK;

        // ---- Q B-frags: B[k=d][n=q], lane&31 = q, 8 d-steps, in registers ----
        bf16x8 qf[8];
        {
            const float* qp = Q + ((size_t)b * T_ + q0 + wave * 32 + l32) * D_ + hi * 8;
            #pragma unroll
            for (int ds = 0; ds < 8; ++ds) {
                const float4* p4 = (const float4*)(qp + ds * 16);
                float4 a = p4[0], c = p4[1];
                __hip_bfloat16 h[8] = {
                    __float2bfloat16(a.x), __float2bfloat16(a.y),
                    __float2bfloat16(a.z), __float2bfloat16(a.w),
                    __float2bfloat16(c.x), __float2bfloat16(c.y),
                    __float2bfloat16(c.z), __float2bfloat16(c.w) };
                qf[ds] = *(const bf16x8*)h;
            }
        }

        f32x16 o[4];                     // O[q][d], 4 d-tiles of 32
        #pragma unroll
        for (int dt = 0; dt < 4; ++dt) o[dt] = zero16();
        float lsum = 0.f;

        const __hip_bfloat16* kb_base = Kb  + (size_t)b * T_ * D_;
        const __hip_bfloat16* vt_base = VTb + (size_t)b * D_ * T_;

        // stage one BK=32 tile (16 KiB total): 16 x 1KB DMA blocks, 4 per wave
        auto stage = [&](int k0s, int buf) {
            #pragma unroll
            for (int it = 0; it < 2; ++it) {
                const int blk = wave * 2 + it;   // 0..7
                {   // K: 1KB = 4 rows x 256B; phys slot p=lane&15 holds logical p^(row&7)
                    const int row = blk * 4 + (lane >> 4);
                    const int s   = (lane & 15) ^ (row & 7);
                    gll16(kb_base + (size_t)(k0s + row) * D_ + s * 8,
                          &sK[buf][0][0] + blk * 512);
                }
                {   // V: 1KB = 16 d-rows x 64B; phys p=lane&3 holds logical p^((row>>1)&3)
                    const int row = blk * 16 + (lane >> 2);
                    const int s   = (lane & 3) ^ ((row >> 1) & 3);
                    gll16(vt_base + (size_t)row * T_ + k0s + s * 8,
                          &sVT[buf][0][0] + blk * 512);
                }
            }
        };

        if (nkb > 0) stage(0, 0);
        __syncthreads();                 // drains DMA (vmcnt 0) + block sync

        int cur = 0;
        for (int kb = 0; kb < nkb; ++kb) {
            const int k0 = kb * BK;
            if (kb + 1 < nkb) stage(k0 + BK, cur ^ 1);   // lands during compute

            // ---- S = K Q^T (swapped): C[m=key][n=q]; swizzled K reads ----
            f32x16 s0 = zero16();
            __builtin_amdgcn_s_setprio(1);
            #pragma unroll
            for (int ds = 0; ds < 8; ++ds) {
                bf16x8 kf = *(const bf16x8*)&sK[cur][l32][(((ds * 2 + hi) ^ (l32 & 7))) * 8];
                s0 = __builtin_amdgcn_mfma_f32_32x32x16_bf16(kf, qf[ds], s0, 0, 0, 0);
            }
            __builtin_amdgcn_s_setprio(0);

            // ---- softmax (fixed-m, exp2) + in-register P->bf16 A-frags ----
            bf16x8 pf[2];
            {
                const int kbase_l = k0 + 4 * hi;
                float p[16];
                #pragma unroll
                for (int r = 0; r < 16; ++r) {
                    int krow = (r & 3) + 8 * (r >> 2);
                    float e = fast_exp2(s0[r] * C);
                    p[r] = (kbase_l + krow < vlen) ? e : 0.f;
                }
                lsum += (((p[0] + p[1]) + (p[2] + p[3])) + ((p[4] + p[5]) + (p[6] + p[7])))
                      + (((p[8] + p[9]) + (p[10] + p[11])) + ((p[12] + p[13]) + (p[14] + p[15])));
                #pragma unroll
                for (int k2 = 0; k2 < 2; ++k2) {
                    const int base = k2 * 8;
                    uint32_t A0 = pk2(p[base + 0], p[base + 1]);
                    uint32_t B0 = pk2(p[base + 4], p[base + 5]);
                    uint32_t A1 = pk2(p[base + 2], p[base + 3]);
                    uint32_t B1 = pk2(p[base + 6], p[base + 7]);
                    plswap(A0, B0);      // word0 / word2
                    plswap(A1, B1);      // word1 / word3
                    union { uint32_t u[4]; bf16x8 v; } fr;
                    fr.u[0] = A0; fr.u[1] = A1; fr.u[2] = B0; fr.u[3] = B1;
                    pf[k2] = fr.v;
                }
            }

            // ---- O += P V : 2 k-steps of 16 keys; swizzled V reads ----
            __builtin_amdgcn_s_setprio(1);
            #pragma unroll
            for (int ks = 0; ks < 2; ++ks)
                #pragma unroll
                for (int dt = 0; dt < 4; ++dt) {
                    const int r = dt * 32 + l32;
                    bf16x8 vf = *(const bf16x8*)&sVT[cur][r][(((ks * 2 + hi) ^ ((r >> 1) & 3))) * 8];
                    o[dt] = __builtin_amdgcn_mfma_f32_32x32x16_bf16(pf[ks], vf, o[dt], 0, 0, 0);
                }
            __builtin_amdgcn_s_setprio(0);

            __syncthreads();             // waits own DMA + all waves done reading cur
            cur ^= 1;
        }

        // ---- epilogue: full row-sum, O / l ; fully-masked (l==0) -> zeros ----
        float ls  = lsum + __shfl_xor(lsum, 32);
        float inv = (ls > 0.f) ? 1.0f / ls : 0.f;     // lane holds inv for q = lane&31
        float invr[16];
        #pragma unroll
        for (int r = 0; r < 16; ++r)
            invr[r] = __shfl(inv, (r & 3) + 8 * (r >> 2) + 4 * hi);
        #pragma unroll
        for (int dt = 0; dt < 4; ++dt)
            #pragma unroll
            for (int r = 0; r < 16; ++r) {
                int q = (r & 3) + 8 * (r >> 2) + 4 * hi;
                out[((size_t)b * T_ + q0 + wave * 32 + q) * D_ + dt * 32 + l32]
                    = o[dt][r] * invr[r];
            }
        // no end-of-task barrier needed: next task's s_task write is fenced by the
        // loop-top pair; sK/sVT reuse is fenced by the last k-iter's barrier.
    }

    // ---- self-reset for next graph replay: last finisher zeroes the queue ----
    if (tid == 0) {
        int d = atomicAdd(&g_done, 1);
        if (d == GRIDP - 1) { atomicExch(&g_ctr, 0); atomicExch(&g_done, 0); }
    }
}

extern "C" void kernel_launch(void* const* d_in, const int* in_sizes, int n_in,
                              void* d_out, int out_size, void* d_ws, size_t ws_size,
                              hipStream_t stream) {
    const float* Q = (const float*)d_in[0];
    const float* K = (const float*)d_in[1];
    const float* V = (const float*)d_in[2];
    const int* vl  = (const int*)d_in[3];
    float* out     = (float*)d_out;

    // ws: Kb bf16 [B][T][D] (16 MiB) | VTb bf16 [B][D][T] (16 MiB)
    const size_t kb_bytes = (size_t)B_ * T_ * D_ * 2;
    if (ws_size < 2 * kb_bytes) return;
    __hip_bfloat16* Kb  = (__hip_bfloat16*)d_ws;
    __hip_bfloat16* VTb = (__hip_bfloat16*)((char*)d_ws + kb_bytes);

    prep     <<<dim3(T_ / 64, B_), 256, 0, stream>>>(K, V, vl, Kb, VTb);
    attn_main<<<dim3(GRIDP), 256, 0, stream>>>(Q, vl, Kb, VTb, out);
}

// Round 4
// 236.735 us; speedup vs baseline: 1.3541x; 1.3541x over previous
//
#include <hip/hip_runtime.h>
#include <hip/hip_bf16.h>
#include <stdint.h>

#define B_ 32
#define T_ 2048
#define D_ 128
#define BQ 64                    // per block: 2 waves x 32 q-rows
#define BK 32
#define NBUF 3                   // triple buffer: compute k | landed k+1 | landing k+2

typedef __attribute__((ext_vector_type(8))) __bf16 bf16x8;
typedef __attribute__((ext_vector_type(16))) float f32x16;

__device__ __forceinline__ float fast_exp2(float x) {
#if __has_builtin(__builtin_amdgcn_exp2f)
    return __builtin_amdgcn_exp2f(x);
#else
    return exp2f(x);
#endif
}

__device__ __forceinline__ f32x16 zero16() {
    f32x16 z;
    #pragma unroll
    for (int i = 0; i < 16; ++i) z[i] = 0.f;
    return z;
}

// pack two f32 -> one u32 of 2x bf16 (compiler emits v_cvt_pk_bf16_f32)
__device__ __forceinline__ uint32_t pk2(float a, float b) {
    union { __hip_bfloat16 h; unsigned short u; } ua, ub;
    ua.h = __float2bfloat16(a); ub.h = __float2bfloat16(b);
    return (uint32_t)ua.u | ((uint32_t)ub.u << 16);
}

// swap lane-halves between two regs (gfx950)
__device__ __forceinline__ void plswap(uint32_t& a, uint32_t& b) {
    asm("v_permlane32_swap_b32 %0, %1" : "+v"(a), "+v"(b));
}

// async global->LDS, 16B per lane, LDS dest = wave-uniform base + lane*16 (linear)
__device__ __forceinline__ void gll16(const __hip_bfloat16* g, __hip_bfloat16* lds) {
    __builtin_amdgcn_global_load_lds(
        (const __attribute__((address_space(1))) uint32_t*)g,
        (__attribute__((address_space(3))) uint32_t*)lds,
        16, 0, 0);
}

// ---------------- fused prep: K fp32->bf16 (same layout) + V fp32 -> VT bf16 [b][d][k] ----------------
__global__ __launch_bounds__(256, 2)
void prep(const float* __restrict__ K, const float* __restrict__ V,
          const int* __restrict__ vlens,
          __hip_bfloat16* __restrict__ Kb, __hip_bfloat16* __restrict__ VTb)
{
    __shared__ float tile[64][132];                // 132: float4-aligned rows
    const int b = blockIdx.y, k0 = blockIdx.x * 64;
    const int kmax = (vlens[b] + 63) & ~63;        // attn never reads past ceil64(vlen)
    if (k0 >= kmax) return;

    // --- K: straight convert, coalesced ---
    {
        const float4* src = (const float4*)(K + ((size_t)b * T_ + k0) * D_);
        uint2* dst = (uint2*)(Kb + ((size_t)b * T_ + k0) * D_);
        #pragma unroll
        for (int it = 0; it < 8; ++it) {
            int c = it * 256 + threadIdx.x;        // 2048 float4 chunks
            float4 v = src[c];
            union { __hip_bfloat16 h[4]; uint2 u; } pk;
            pk.h[0] = __float2bfloat16(v.x); pk.h[1] = __float2bfloat16(v.y);
            pk.h[2] = __float2bfloat16(v.z); pk.h[3] = __float2bfloat16(v.w);
            dst[c] = pk.u;
        }
    }

    // --- V: LDS transpose ---
    {
        const float4* src = (const float4*)(V + ((size_t)b * T_ + k0) * D_);
        #pragma unroll
        for (int it = 0; it < 8; ++it) {
            int c = it * 256 + threadIdx.x;
            int row = c >> 5, c4 = c & 31;
            *(float4*)&tile[row][c4 * 4] = src[c];
        }
        __syncthreads();
        #pragma unroll
        for (int it = 0; it < 8; ++it) {
            int c = it * 256 + threadIdx.x;        // 2048 chunks of 4 keys
            int kc = c & 15, d = c >> 4;
            union { __hip_bfloat16 h[4]; uint2 u; } pk;
            #pragma unroll
            for (int j = 0; j < 4; ++j) {
                int jj = (j + kc) & 3;             // rotate reads to spread LDS banks
                pk.h[jj] = __float2bfloat16(tile[kc * 4 + jj][d]);
            }
            *(uint2*)(VTb + ((size_t)b * D_ + d) * T_ + k0 + kc * 4) = pk.u;
        }
    }
}

// ---------------- main: flash attention, 2 waves x 32 q-rows (BQ=64), BK=32, 32x32x16 MFMA ----------------
// SWAPPED QK^T: S = mfma(K, Q) -> C[m=key][n=q], col(lane&31)=q, row=key via
// (r&3)+8*(r>>2)+4*hi [harness-verified r1-r3]. Lane owns P[*][q=lane&31] ->
// softmax + P->bf16 A-frags in-register (pk2 + permlane32_swap). Staging via
// global_load_lds; both-sides XOR swizzle (K rows 256B: s^(row&7); V rows 64B:
// s^((row>>1)&3)) [verified r3].
// NEW: triple buffer + raw s_barrier + COUNTED vmcnt(8) (T3/T4): the barrier
// never drains the just-issued prefetch (vmcnt reaches 0 only in the tail).
// Steady state per iter: [issue stage(k+2)] [vmcnt(8): retires stage(k+1),
// stage(k) retired last iter] [sched_barrier] [compute k] [fence] [s_barrier].
// Grid 1024 blocks > residency 768 (48KiB LDS -> 3 blocks/CU) -> HW dispatcher
// rebalances variable-vlen work. blockIdx.x = qblock: concurrent blocks share
// one batch's ~1MB K/V set (L2).
// __launch_bounds__(128,2): 256-reg cap -- rounds 1&3 proved tighter caps spill
// (WRITE_SIZE canary).
__global__ __launch_bounds__(128, 2)
void attn_main(const float* __restrict__ Q, const int* __restrict__ vlens,
               const __hip_bfloat16* __restrict__ Kb,
               const __hip_bfloat16* __restrict__ VTb,
               float* __restrict__ out)
{
    const int tid  = threadIdx.x;
    const int wave = tid >> 6;          // 0..1, owns q-rows [wave*32, wave*32+32)
    const int lane = tid & 63;
    const int l32  = lane & 31;
    const int hi   = lane >> 5;

    const int b    = blockIdx.y;
    const int q0   = blockIdx.x * BQ;
    const int vlen = vlens[b];
    const int nkb  = (vlen + BK - 1) / BK;

    __shared__ __hip_bfloat16 sK [NBUF][BK][128];   // K tile [key][d]  3x8 KiB
    __shared__ __hip_bfloat16 sVT[NBUF][128][BK];   // V tile [d][key]  3x8 KiB

    const float C = 1.4426950408889634f / 256.0f;   // log2(e) / (2*d)

    // ---- Q B-frags: B[k=d][n=q], lane&31 = q, 8 d-steps, in registers ----
    bf16x8 qf[8];
    {
        const float* qp = Q + ((size_t)b * T_ + q0 + wave * 32 + l32) * D_ + hi * 8;
        #pragma unroll
        for (int ds = 0; ds < 8; ++ds) {
            const float4* p4 = (const float4*)(qp + ds * 16);
            float4 a = p4[0], c = p4[1];
            __hip_bfloat16 h[8] = {
                __float2bfloat16(a.x), __float2bfloat16(a.y),
                __float2bfloat16(a.z), __float2bfloat16(a.w),
                __float2bfloat16(c.x), __float2bfloat16(c.y),
                __float2bfloat16(c.z), __float2bfloat16(c.w) };
            qf[ds] = *(const bf16x8*)h;
        }
    }

    f32x16 o[4];                     // O[q][d], 4 d-tiles of 32
    #pragma unroll
    for (int dt = 0; dt < 4; ++dt) o[dt] = zero16();
    float lsum = 0.f;

    const __hip_bfloat16* kb_base = Kb  + (size_t)b * T_ * D_;
    const __hip_bfloat16* vt_base = VTb + (size_t)b * D_ * T_;

    // stage one BK=32 tile (16 KiB = 16 x 1KB DMA blocks, 8 per wave -> 8 vmcnt events)
    auto stage = [&](int k0s, int buf) {
        #pragma unroll
        for (int it = 0; it < 4; ++it) {
            const int blk = wave * 4 + it;   // 0..7
            {   // K: 1KB = 4 rows x 256B; phys slot p=lane&15 holds logical p^(row&7)
                const int row = blk * 4 + (lane >> 4);
                const int s   = (lane & 15) ^ (row & 7);
                gll16(kb_base + (size_t)(k0s + row) * D_ + s * 8,
                      &sK[buf][0][0] + blk * 512);
            }
            {   // V: 1KB = 16 d-rows x 64B; phys p=lane&3 holds logical p^((row>>1)&3)
                const int row = blk * 16 + (lane >> 2);
                const int s   = (lane & 3) ^ ((row >> 1) & 3);
                gll16(vt_base + (size_t)row * T_ + k0s + s * 8,
                      &sVT[buf][0][0] + blk * 512);
            }
        }
    };

    // ---- prologue: fill buffers 0 and 1; retire stage(0); one barrier ----
    if (nkb > 0) stage(0, 0);
    if (nkb > 1) {
        stage(BK, 1);
        asm volatile("s_waitcnt vmcnt(8)" ::: "memory");   // stage(0) done, stage(1) in flight
    } else {
        asm volatile("s_waitcnt vmcnt(0)" ::: "memory");
    }
    __builtin_amdgcn_s_barrier();

    int cur = 0;
    for (int kb = 0; kb < nkb; ++kb) {
        const int k0 = kb * BK;

        // ---- issue stage(k+2) into the buffer freed by iter k-1 (barrier-protected) ----
        if (kb + 2 < nkb) {
            int nxt2 = cur + 2; if (nxt2 >= NBUF) nxt2 -= NBUF;
            stage(k0 + 2 * BK, nxt2);
        }
        // ---- counted wait: retire everything except the newest 8 (stage k+1) ----
        if (kb + 1 < nkb) asm volatile("s_waitcnt vmcnt(8)" ::: "memory");
        else              asm volatile("s_waitcnt vmcnt(0)" ::: "memory");
        __builtin_amdgcn_sched_barrier(0);

        // ---- S = K Q^T (swapped): C[m=key][n=q]; swizzled K reads ----
        f32x16 s0 = zero16();
        __builtin_amdgcn_s_setprio(1);
        #pragma unroll
        for (int ds = 0; ds < 8; ++ds) {
            bf16x8 kf = *(const bf16x8*)&sK[cur][l32][(((ds * 2 + hi) ^ (l32 & 7))) * 8];
            s0 = __builtin_amdgcn_mfma_f32_32x32x16_bf16(kf, qf[ds], s0, 0, 0, 0);
        }
        __builtin_amdgcn_s_setprio(0);

        // ---- softmax (fixed-m, exp2) + in-register P->bf16 A-frags ----
        bf16x8 pf[2];
        {
            const int kbase_l = k0 + 4 * hi;
            float p[16];
            #pragma unroll
            for (int r = 0; r < 16; ++r) {
                int krow = (r & 3) + 8 * (r >> 2);
                float e = fast_exp2(s0[r] * C);
                p[r] = (kbase_l + krow < vlen) ? e : 0.f;
            }
            lsum += (((p[0] + p[1]) + (p[2] + p[3])) + ((p[4] + p[5]) + (p[6] + p[7])))
                  + (((p[8] + p[9]) + (p[10] + p[11])) + ((p[12] + p[13]) + (p[14] + p[15])));
            #pragma unroll
            for (int k2 = 0; k2 < 2; ++k2) {
                const int base = k2 * 8;
                uint32_t A0 = pk2(p[base + 0], p[base + 1]);
                uint32_t B0 = pk2(p[base + 4], p[base + 5]);
                uint32_t A1 = pk2(p[base + 2], p[base + 3]);
                uint32_t B1 = pk2(p[base + 6], p[base + 7]);
                plswap(A0, B0);      // word0 / word2
                plswap(A1, B1);      // word1 / word3
                union { uint32_t u[4]; bf16x8 v; } fr;
                fr.u[0] = A0; fr.u[1] = A1; fr.u[2] = B0; fr.u[3] = B1;
                pf[k2] = fr.v;
            }
        }

        // ---- O += P V : 2 k-steps of 16 keys; swizzled V reads ----
        __builtin_amdgcn_s_setprio(1);
        #pragma unroll
        for (int ks = 0; ks < 2; ++ks)
            #pragma unroll
            for (int dt = 0; dt < 4; ++dt) {
                const int r = dt * 32 + l32;
                bf16x8 vf = *(const bf16x8*)&sVT[cur][r][(((ks * 2 + hi) ^ ((r >> 1) & 3))) * 8];
                o[dt] = __builtin_amdgcn_mfma_f32_32x32x16_bf16(pf[ks], vf, o[dt], 0, 0, 0);
            }
        __builtin_amdgcn_s_setprio(0);

        // ---- end-of-iter barrier: all waves done reading buf[cur] before it is
        //      re-targeted by next iter's stage. Compiler-only fence (NO vmcnt drain). ----
        asm volatile("" ::: "memory");
        __builtin_amdgcn_s_barrier();
        cur = (cur == NBUF - 1) ? 0 : cur + 1;
    }

    // ---- epilogue: full row-sum, O / l ; fully-masked (l==0) -> zeros ----
    float ls  = lsum + __shfl_xor(lsum, 32);
    float inv = (ls > 0.f) ? 1.0f / ls : 0.f;     // lane holds inv for q = lane&31
    float invr[16];
    #pragma unroll
    for (int r = 0; r < 16; ++r)
        invr[r] = __shfl(inv, (r & 3) + 8 * (r >> 2) + 4 * hi);
    #pragma unroll
    for (int dt = 0; dt < 4; ++dt)
        #pragma unroll
        for (int r = 0; r < 16; ++r) {
            int q = (r & 3) + 8 * (r >> 2) + 4 * hi;
            out[((size_t)b * T_ + q0 + wave * 32 + q) * D_ + dt * 32 + l32]
                = o[dt][r] * invr[r];
        }
}

extern "C" void kernel_launch(void* const* d_in, const int* in_sizes, int n_in,
                              void* d_out, int out_size, void* d_ws, size_t ws_size,
                              hipStream_t stream) {
    const float* Q = (const float*)d_in[0];
    const float* K = (const float*)d_in[1];
    const float* V = (const float*)d_in[2];
    const int* vl  = (const int*)d_in[3];
    float* out     = (float*)d_out;

    // ws: Kb bf16 [B][T][D] (16 MiB) | VTb bf16 [B][D][T] (16 MiB)
    const size_t kb_bytes = (size_t)B_ * T_ * D_ * 2;
    if (ws_size < 2 * kb_bytes) return;
    __hip_bfloat16* Kb  = (__hip_bfloat16*)d_ws;
    __hip_bfloat16* VTb = (__hip_bfloat16*)((char*)d_ws + kb_bytes);

    prep     <<<dim3(T_ / 64, B_), 256, 0, stream>>>(K, V, vl, Kb, VTb);
    // x = qblock (fastest): concurrent blocks share a batch's K/V in L2;
    // grid 1024 > residency 768 -> dispatcher load-balances variable vlen.
    attn_main<<<dim3(T_ / BQ, B_), 128, 0, stream>>>(Q, vl, Kb, VTb, out);
}

// Round 6
// 224.802 us; speedup vs baseline: 1.4260x; 1.0531x over previous
//
#include <hip/hip_runtime.h>
#include <hip/hip_bf16.h>
#include <stdint.h>

#define B_ 32
#define T_ 2048
#define D_ 128
#define BQ 128                   // per block: 4 waves x 32 q-rows
#define BK 32
#define NBUF 3                   // compute k | k+1 landed | k+2 landing

typedef __attribute__((ext_vector_type(8))) __bf16 bf16x8;
typedef __attribute__((ext_vector_type(16))) float f32x16;

__device__ __forceinline__ float fast_exp2(float x) {
#if __has_builtin(__builtin_amdgcn_exp2f)
    return __builtin_amdgcn_exp2f(x);
#else
    return exp2f(x);
#endif
}

__device__ __forceinline__ f32x16 zero16() {
    f32x16 z;
    #pragma unroll
    for (int i = 0; i < 16; ++i) z[i] = 0.f;
    return z;
}

// pack two f32 -> one u32 of 2x bf16 (compiler emits v_cvt_pk_bf16_f32)
__device__ __forceinline__ uint32_t pk2(float a, float b) {
    union { __hip_bfloat16 h; unsigned short u; } ua, ub;
    ua.h = __float2bfloat16(a); ub.h = __float2bfloat16(b);
    return (uint32_t)ua.u | ((uint32_t)ub.u << 16);
}

// swap lane-halves between two regs (gfx950)
__device__ __forceinline__ void plswap(uint32_t& a, uint32_t& b) {
    asm("v_permlane32_swap_b32 %0, %1" : "+v"(a), "+v"(b));
}

// async global->LDS, 16B per lane, LDS dest = wave-uniform base + lane*16 (linear)
__device__ __forceinline__ void gll16(const __hip_bfloat16* g, __hip_bfloat16* lds) {
    __builtin_amdgcn_global_load_lds(
        (const __attribute__((address_space(1))) uint32_t*)g,
        (__attribute__((address_space(3))) uint32_t*)lds,
        16, 0, 0);
}

// ---------------- fused prep: K fp32->bf16 (same layout) + V fp32 -> VT bf16 [b][d][k] ----------------
__global__ __launch_bounds__(256, 2)
void prep(const float* __restrict__ K, const float* __restrict__ V,
          const int* __restrict__ vlens,
          __hip_bfloat16* __restrict__ Kb, __hip_bfloat16* __restrict__ VTb)
{
    __shared__ float tile[64][132];                // 132: float4-aligned rows
    const int b = blockIdx.y, k0 = blockIdx.x * 64;
    const int kmax = (vlens[b] + 63) & ~63;        // attn never reads past ceil64(vlen)
    if (k0 >= kmax) return;

    // --- K: straight convert, coalesced ---
    {
        const float4* src = (const float4*)(K + ((size_t)b * T_ + k0) * D_);
        uint2* dst = (uint2*)(Kb + ((size_t)b * T_ + k0) * D_);
        #pragma unroll
        for (int it = 0; it < 8; ++it) {
            int c = it * 256 + threadIdx.x;        // 2048 float4 chunks
            float4 v = src[c];
            union { __hip_bfloat16 h[4]; uint2 u; } pk;
            pk.h[0] = __float2bfloat16(v.x); pk.h[1] = __float2bfloat16(v.y);
            pk.h[2] = __float2bfloat16(v.z); pk.h[3] = __float2bfloat16(v.w);
            dst[c] = pk.u;
        }
    }

    // --- V: LDS transpose ---
    {
        const float4* src = (const float4*)(V + ((size_t)b * T_ + k0) * D_);
        #pragma unroll
        for (int it = 0; it < 8; ++it) {
            int c = it * 256 + threadIdx.x;
            int row = c >> 5, c4 = c & 31;
            *(float4*)&tile[row][c4 * 4] = src[c];
        }
        __syncthreads();
        #pragma unroll
        for (int it = 0; it < 8; ++it) {
            int c = it * 256 + threadIdx.x;        // 2048 chunks of 4 keys
            int kc = c & 15, d = c >> 4;
            union { __hip_bfloat16 h[4]; uint2 u; } pk;
            #pragma unroll
            for (int j = 0; j < 4; ++j) {
                int jj = (j + kc) & 3;             // rotate reads to spread LDS banks
                pk.h[jj] = __float2bfloat16(tile[kc * 4 + jj][d]);
            }
            *(uint2*)(VTb + ((size_t)b * D_ + d) * T_ + k0 + kc * 4) = pk.u;
        }
    }
}

// ---------------- main: flash attention, 4 waves x 32 q-rows (BQ=128), BK=32, 32x32x16 MFMA ----------------
// SWAPPED QK^T: S = mfma(K, Q) -> C[m=key][n=q], col(lane&31)=q, row=key via
// (r&3)+8*(r>>2)+4*hi [harness-verified r1-r4]. Lane owns P[*][q=lane&31] ->
// softmax + P->bf16 A-frags in-register (pk2 + permlane32_swap). Row-sum via
// mfma(pf, ones, lacc): lacc has o's layout -> epilogue is per-reg multiply.
// Staging: global_load_lds, persistent per-thread source pointers, both-sides
// XOR swizzle (K rows 256B: s^(row&7); V rows 64B: s^((row>>1)&3)) [r3/r4].
//
// PIPELINE SAFETY INVARIANT (r5's race, fixed): a wave must retire its own
// DMA ops for tile kb BEFORE the s_barrier ending iter kb-1, because other
// waves read this wave's staged blocks at iter kb and only the barrier
// publishes them. Hence the wait at iter kb retires THROUGH tile kb+1:
// steady-state vmcnt(4) (leaves only the just-issued stage(kb+2)), tail
// vmcnt(0). Prologue: stage(0..1), vmcnt(4) retires tile 0, s_barrier.
// NBUF=3 -> LDS 48 KiB -> 3 blocks/CU (12 waves/CU); capacity 768 > grid 512
// gives the dispatcher slack for variable-vlen imbalance.
__global__ __launch_bounds__(256, 2)
void attn_main(const float* __restrict__ Q, const int* __restrict__ vlens,
               const __hip_bfloat16* __restrict__ Kb,
               const __hip_bfloat16* __restrict__ VTb,
               float* __restrict__ out)
{
    const int tid  = threadIdx.x;
    const int wave = tid >> 6;          // 0..3, owns q-rows [wave*32, wave*32+32)
    const int lane = tid & 63;
    const int l32  = lane & 31;
    const int hi   = lane >> 5;

    const int b    = blockIdx.y;
    const int q0   = blockIdx.x * BQ;
    const int vlen = vlens[b];
    const int nkb  = (vlen + BK - 1) / BK;

    __shared__ __hip_bfloat16 sK [NBUF][BK][128];   // K tile [key][d]  3x8 KiB
    __shared__ __hip_bfloat16 sVT[NBUF][128][BK];   // V tile [d][key]  3x8 KiB
    __hip_bfloat16* sKf = &sK [0][0][0];
    __hip_bfloat16* sVf = &sVT[0][0][0];

    const float C = 1.4426950408889634f / 256.0f;   // log2(e) / (2*d)

    // ---- Q B-frags: B[k=d][n=q], lane&31 = q, 8 d-steps, in registers ----
    bf16x8 qf[8];
    {
        const float* qp = Q + ((size_t)b * T_ + q0 + wave * 32 + l32) * D_ + hi * 8;
        #pragma unroll
        for (int ds = 0; ds < 8; ++ds) {
            const float4* p4 = (const float4*)(qp + ds * 16);
            float4 a = p4[0], c = p4[1];
            __hip_bfloat16 h[8] = {
                __float2bfloat16(a.x), __float2bfloat16(a.y),
                __float2bfloat16(a.z), __float2bfloat16(a.w),
                __float2bfloat16(c.x), __float2bfloat16(c.y),
                __float2bfloat16(c.z), __float2bfloat16(c.w) };
            qf[ds] = *(const bf16x8*)h;
        }
    }

    bf16x8 ones;
    #pragma unroll
    for (int j = 0; j < 8; ++j) ones[j] = (__bf16)1.0f;

    f32x16 o[4];                     // O[q][d], 4 d-tiles of 32
    #pragma unroll
    for (int dt = 0; dt < 4; ++dt) o[dt] = zero16();
    f32x16 lacc = zero16();          // row-sums, same layout as o

    // ---- persistent staging pointers: advance one BK-tile per stage call ----
    const __hip_bfloat16* kb_base = Kb  + (size_t)b * T_ * D_;
    const __hip_bfloat16* vt_base = VTb + (size_t)b * D_ * T_;
    const int kr0 = (wave * 2 + 0) * 4 + (lane >> 4);
    const int kr1 = (wave * 2 + 1) * 4 + (lane >> 4);
    const int vr0 = (wave * 2 + 0) * 16 + (lane >> 2);
    const int vr1 = (wave * 2 + 1) * 16 + (lane >> 2);
    const __hip_bfloat16* kp0 = kb_base + (size_t)kr0 * D_ + (((lane & 15) ^ (kr0 & 7)) * 8);
    const __hip_bfloat16* kp1 = kb_base + (size_t)kr1 * D_ + (((lane & 15) ^ (kr1 & 7)) * 8);
    const __hip_bfloat16* vp0 = vt_base + (size_t)vr0 * T_ + (((lane & 3) ^ ((vr0 >> 1) & 3)) * 8);
    const __hip_bfloat16* vp1 = vt_base + (size_t)vr1 * T_ + (((lane & 3) ^ ((vr1 >> 1) & 3)) * 8);

    // stage one BK=32 tile: 16 x 1KB DMA blocks, 4 gll16/thread = 4 vmcnt events
    auto stage = [&](int buf) {
        gll16(kp0, sKf + buf * (BK * 128) + (wave * 2 + 0) * 512); kp0 += (size_t)BK * D_;
        gll16(vp0, sVf + buf * (128 * BK) + (wave * 2 + 0) * 512); vp0 += BK;
        gll16(kp1, sKf + buf * (BK * 128) + (wave * 2 + 1) * 512); kp1 += (size_t)BK * D_;
        gll16(vp1, sVf + buf * (128 * BK) + (wave * 2 + 1) * 512); vp1 += BK;
    };

    // ---- prologue: stage tiles 0,1; retire tile 0 (pre-barrier!); publish ----
    if (nkb > 0) stage(0);
    if (nkb > 1) {
        stage(1);
        asm volatile("s_waitcnt vmcnt(4)" ::: "memory");   // tile 0 retired, tile 1 in flight
    } else if (nkb > 0) {
        asm volatile("s_waitcnt vmcnt(0)" ::: "memory");
    }
    __builtin_amdgcn_s_barrier();

    int cur = 0;
    for (int kb = 0; kb < nkb; ++kb) {
        const int k0 = kb * BK;

        // issue stage(kb+2) into buf (kb+2)%3 == (kb-1)%3 (freed by barrier kb-1)
        if (kb + 2 < nkb) {
            int tb = cur + 2; if (tb >= NBUF) tb -= NBUF;
            stage(tb);
        }
        // wait retires THROUGH tile kb+1 (invariant above); vmcnt(4) leaves only
        // the just-issued stage(kb+2) in flight.
        if (kb + 2 < nkb) asm volatile("s_waitcnt vmcnt(4)" ::: "memory");
        else              asm volatile("s_waitcnt vmcnt(0)" ::: "memory");
        __builtin_amdgcn_sched_barrier(0);

        // ---- S = K Q^T (swapped): C[m=key][n=q]; swizzled K reads ----
        f32x16 s0 = zero16();
        __builtin_amdgcn_s_setprio(1);
        #pragma unroll
        for (int ds = 0; ds < 8; ++ds) {
            bf16x8 kf = *(const bf16x8*)&sK[cur][l32][(((ds * 2 + hi) ^ (l32 & 7))) * 8];
            s0 = __builtin_amdgcn_mfma_f32_32x32x16_bf16(kf, qf[ds], s0, 0, 0, 0);
        }
        __builtin_amdgcn_s_setprio(0);

        // ---- softmax (fixed-m, exp2) + in-register P->bf16 A-frags ----
        bf16x8 pf[2];
        {
            const int kbase_l = k0 + 4 * hi;
            float p[16];
            #pragma unroll
            for (int r = 0; r < 16; ++r) {
                int krow = (r & 3) + 8 * (r >> 2);
                float e = fast_exp2(s0[r] * C);
                p[r] = (kbase_l + krow < vlen) ? e : 0.f;
            }
            #pragma unroll
            for (int k2 = 0; k2 < 2; ++k2) {
                const int base = k2 * 8;
                uint32_t A0 = pk2(p[base + 0], p[base + 1]);
                uint32_t B0 = pk2(p[base + 4], p[base + 5]);
                uint32_t A1 = pk2(p[base + 2], p[base + 3]);
                uint32_t B1 = pk2(p[base + 6], p[base + 7]);
                plswap(A0, B0);      // word0 / word2
                plswap(A1, B1);      // word1 / word3
                union { uint32_t u[4]; bf16x8 v; } fr;
                fr.u[0] = A0; fr.u[1] = A1; fr.u[2] = B0; fr.u[3] = B1;
                pf[k2] = fr.v;
            }
        }

        // ---- O += P V ; lacc += P*1 : 2 k-steps of 16 keys; swizzled V reads ----
        __builtin_amdgcn_s_setprio(1);
        #pragma unroll
        for (int ks = 0; ks < 2; ++ks) {
            lacc = __builtin_amdgcn_mfma_f32_32x32x16_bf16(pf[ks], ones, lacc, 0, 0, 0);
            #pragma unroll
            for (int dt = 0; dt < 4; ++dt) {
                const int r = dt * 32 + l32;
                bf16x8 vf = *(const bf16x8*)&sVT[cur][r][(((ks * 2 + hi) ^ ((r >> 1) & 3))) * 8];
                o[dt] = __builtin_amdgcn_mfma_f32_32x32x16_bf16(pf[ks], vf, o[dt], 0, 0, 0);
            }
        }
        __builtin_amdgcn_s_setprio(0);

        // end-of-iter barrier: publishes this wave's retired tile kb+1 writes and
        // frees buf[cur] for the stage issued next iter. NO vmcnt drain here.
        asm volatile("" ::: "memory");
        __builtin_amdgcn_s_barrier();
        cur = (cur == NBUF - 1) ? 0 : cur + 1;
    }

    // ---- epilogue: O / l per register (lacc layout == o layout); l==0 -> 0 ----
    float invr[16];
    #pragma unroll
    for (int r = 0; r < 16; ++r) invr[r] = (lacc[r] > 0.f) ? 1.0f / lacc[r] : 0.f;
    #pragma unroll
    for (int dt = 0; dt < 4; ++dt)
        #pragma unroll
        for (int r = 0; r < 16; ++r) {
            int q = (r & 3) + 8 * (r >> 2) + 4 * hi;
            out[((size_t)b * T_ + q0 + wave * 32 + q) * D_ + dt * 32 + l32]
                = o[dt][r] * invr[r];
        }
}

extern "C" void kernel_launch(void* const* d_in, const int* in_sizes, int n_in,
                              void* d_out, int out_size, void* d_ws, size_t ws_size,
                              hipStream_t stream) {
    const float* Q = (const float*)d_in[0];
    const float* K = (const float*)d_in[1];
    const float* V = (const float*)d_in[2];
    const int* vl  = (const int*)d_in[3];
    float* out     = (float*)d_out;

    // ws: Kb bf16 [B][T][D] (16 MiB) | VTb bf16 [B][D][T] (16 MiB)
    const size_t kb_bytes = (size_t)B_ * T_ * D_ * 2;
    if (ws_size < 2 * kb_bytes) return;
    __hip_bfloat16* Kb  = (__hip_bfloat16*)d_ws;
    __hip_bfloat16* VTb = (__hip_bfloat16*)((char*)d_ws + kb_bytes);

    prep     <<<dim3(T_ / 64, B_), 256, 0, stream>>>(K, V, vl, Kb, VTb);
    // x = qblock (fastest): concurrent blocks share a batch's K/V in L2.
    attn_main<<<dim3(T_ / BQ, B_), 256, 0, stream>>>(Q, vl, Kb, VTb, out);
}